// Round 2
// 149.825 us; speedup vs baseline: 1.3740x; 1.3740x over previous
//
#include <hip/hip_runtime.h>
#include <cstddef>

#define BB 4
#define CC 256
#define NN 4096
#define NI 32

typedef __attribute__((ext_vector_type(8))) short bf16x8;   // 8 bf16 = 4 VGPRs
typedef __attribute__((ext_vector_type(16))) float f32x16;  // MFMA 32x32 acc
typedef __attribute__((ext_vector_type(4))) float f32x4;    // indexable float4
typedef unsigned short ushort_t;
typedef unsigned int uint32;

typedef union { uint32 u[4]; bf16x8 v; } fragU;

__device__ __forceinline__ uint32 f2bf_bits(float f) {
    union { float f; uint32 u; } v; v.f = f;
    return (v.u + 0x7fffu + ((v.u >> 16) & 1u)) >> 16;   // RNE
}
__device__ __forceinline__ uint32 pack2bf(float a, float b) {
    return f2bf_bits(a) | (f2bf_bits(b) << 16);
}
// truncation pack (round-toward-zero): 2-3 VALU ops vs 8 for RNE. P-only.
__device__ __forceinline__ uint32 pack2bf_t(float a, float b) {
    union { float f; uint32 u; } A, B; A.f = a; B.f = b;
    return (B.u & 0xFFFF0000u) | (A.u >> 16);
}

// V fragment-order layout: vF[b][n/16][(n>>3)&1][c][n&7] (bf16)
// -> PV B-frag load is 16B/lane, lane-stride 16B (perfectly coalesced).
__device__ __forceinline__ size_t vfidx(int b, int n, int c) {
    return ((((size_t)b * (NN / 16) + (n >> 4)) * 2 + ((n >> 3) & 1)) * (CC * 8))
           + (size_t)c * 8 + (n & 7);
}

// ---------------------------------------------------------------- weight pre-convert
// wvF layout: ((ot*16 + kkg)*64 + lane)*8 + j  holds  wv[o][k] with
//   o = ot*32 + (lane&31), k = kkg*16 + (lane>>5)*8 + j.
// This single layout serves as BOTH an MFMA A-frag (m = lane&31) and B-frag
// (n = lane&31) — the two operand lane maps are identical (verified by the
// attn kernel, which feeds the same qT/kT layout as both A and B).
// wqF/wkF: (kkg*64 + lane)*8 + j  (o in 0..31).
__global__ __launch_bounds__(256) void wconv_kernel(
    const float* __restrict__ wq, const float* __restrict__ wk,
    const float* __restrict__ wv,
    ushort_t* __restrict__ wqF, ushort_t* __restrict__ wkF,
    ushort_t* __restrict__ wvF)
{
    const int bid = blockIdx.x;
    const int t = threadIdx.x;
    if (bid < 64) {                       // wv: 256x256 = 16384 float4
        const int fi = bid * 256 + t;
        const int o  = fi >> 6;           // 0..255
        const int k4 = (fi & 63) * 4;     // 0..252
        const f32x4 x = *(const f32x4*)&wv[(size_t)o * CC + k4];
        const int kkg = k4 >> 4, hh = (k4 >> 3) & 1, j0 = k4 & 7;
        const int ot = o >> 5, lane = hh * 32 + (o & 31);
        uint2 p; p.x = pack2bf(x[0], x[1]); p.y = pack2bf(x[2], x[3]);
        *(uint2*)&wvF[((size_t)(ot * 16 + kkg) * 64 + lane) * 8 + j0] = p;
    } else {                              // wq / wk: 32x256 each = 2048 float4
        const int which = (bid - 64) >> 1;        // 0=q, 1=k
        const int part  = (bid - 64) & 1;
        const float* src = which ? wk : wq;
        ushort_t* dst = which ? wkF : wqF;
#pragma unroll
        for (int p = 0; p < 4; ++p) {
            const int fi = part * 1024 + p * 256 + t;   // 0..2047
            const int o  = fi >> 6;                     // 0..31
            const int k4 = (fi & 63) * 4;
            const f32x4 x = *(const f32x4*)&src[(size_t)o * CC + k4];
            const int kkg = k4 >> 4, hh = (k4 >> 3) & 1, j0 = k4 & 7;
            const int lane = hh * 32 + (o & 31);
            uint2 pr; pr.x = pack2bf(x[0], x[1]); pr.y = pack2bf(x[2], x[3]);
            *(uint2*)&dst[((size_t)kkg * 64 + lane) * 8 + j0] = pr;
        }
    }
}

// ---------------------------------------------------------------- fused Q/K/V projection (MFMA)
// Grid (NN/64, B), 256 thr / 4 waves. Per block: 64 tokens, all outputs.
// K-loop: 4 chunks of BK=64 channels. feat/edge staged to LDS as bf16 frags
// (row-pair packing -> ds_write_b32, frag read = ds_read_b128). Weight frags
// come straight from global (L2-resident, coalesced 16B/lane).
//   Q (waves 0,1): acc = mfma(A=wqF, B=featFrag[nt=w])   -> rows=i, col=token
//   K (waves 2,3): acc = mfma(A=wkF, B=edgeFrag[nt=w-2]) -> rows=i, col=token
//   V (all):       acc = mfma(A=edgeFrag[mt], B=wvF[ct]) -> rows=token, col=o
// V operand order makes each reg-quad 4 CONSECUTIVE tokens -> uint2 stores
// land contiguously in vfidx order (wave store = contiguous 512B span).
__global__ __launch_bounds__(256, 2) void proj_kernel(
    const float* __restrict__ feat, const float* __restrict__ edge,
    const ushort_t* __restrict__ wqF, const ushort_t* __restrict__ wkF,
    const ushort_t* __restrict__ wvF,
    const float* __restrict__ bq, const float* __restrict__ bk,
    const float* __restrict__ bv,
    ushort_t* __restrict__ qT, ushort_t* __restrict__ kT,
    ushort_t* __restrict__ vF)
{
    __shared__ __attribute__((aligned(16))) uint32 sF[4][2][64][4];  // 8 KB
    __shared__ __attribute__((aligned(16))) uint32 sE[4][2][64][4];  // 8 KB

    const int tid = threadIdx.x;
    const int b = blockIdx.y;
    const int n0 = blockIdx.x * 64;
    const int w = tid >> 6, lane = tid & 63;
    const int col = lane & 31, h = lane >> 5;

    // per-wave global frag pointers
    const ushort_t* __restrict__ aQK = ((w < 2) ? wqF : wkF) + (size_t)lane * 8;
    const ushort_t* __restrict__ wvB0 = wvF + ((size_t)((2 * w + 0) * 16) * 64 + lane) * 8;
    const ushort_t* __restrict__ wvB1 = wvF + ((size_t)((2 * w + 1) * 16) * 64 + lane) * 8;
    const uint32* __restrict__ bSrc =
        (w == 0) ? &sF[0][0][lane][0] :
        (w == 1) ? &sF[0][1][lane][0] :
        (w == 2) ? &sE[0][0][lane][0] : &sE[0][1][lane][0];

    f32x16 accV[2][2];   // [token-tile mt][channel-tile cti]
    f32x16 accS;         // Q or K tile (per wave)
#pragma unroll
    for (int r = 0; r < 16; ++r) {
        accS[r] = 0.f;
        accV[0][0][r] = 0.f; accV[0][1][r] = 0.f;
        accV[1][0][r] = 0.f; accV[1][1][r] = 0.f;
    }

    // staging registers: 2 passes x row-pair x 4 floats, feat + edge
    f32x4 rF[2][2], rE[2][2];

    // prologue: load chunk 0
#pragma unroll
    for (int p = 0; p < 2; ++p) {
        const int pi = p * 256 + tid;
        const int m = pi >> 4, cidx = pi & 15;
        const size_t ga = ((size_t)(b * CC + 2 * m)) * NN + n0 + cidx * 4;
        rF[p][0] = *(const f32x4*)&feat[ga];
        rF[p][1] = *(const f32x4*)&feat[ga + NN];
        rE[p][0] = *(const f32x4*)&edge[ga];
        rE[p][1] = *(const f32x4*)&edge[ga + NN];
    }

    for (int ch = 0; ch < 4; ++ch) {
        // ---- stage regs -> LDS bf16 frags (row-pair: k=2m low half, 2m+1 high)
#pragma unroll
        for (int p = 0; p < 2; ++p) {
            const int pi = p * 256 + tid;
            const int m = pi >> 4, cidx = pi & 15;
            const int kk = m >> 3, hh = (m >> 2) & 1, ju = m & 3;
#pragma unroll
            for (int c = 0; c < 4; ++c) {
                const int cn = cidx * 4 + c;
                const int nt = cn >> 5, cl = cn & 31;
                sF[kk][nt][hh * 32 + cl][ju] = pack2bf(rF[p][0][c], rF[p][1][c]);
                sE[kk][nt][hh * 32 + cl][ju] = pack2bf(rE[p][0][c], rE[p][1][c]);
            }
        }
        __syncthreads();

        // ---- issue next chunk's global loads (overlap MFMA below)
        if (ch < 3) {
            const int c0 = (ch + 1) * 64;
#pragma unroll
            for (int p = 0; p < 2; ++p) {
                const int pi = p * 256 + tid;
                const int m = pi >> 4, cidx = pi & 15;
                const size_t ga = ((size_t)(b * CC + c0 + 2 * m)) * NN + n0 + cidx * 4;
                rF[p][0] = *(const f32x4*)&feat[ga];
                rF[p][1] = *(const f32x4*)&feat[ga + NN];
                rE[p][0] = *(const f32x4*)&edge[ga];
                rE[p][1] = *(const f32x4*)&edge[ga + NN];
            }
        }

        // ---- MFMA over the 4 k-steps of this chunk
#pragma unroll
        for (int kk = 0; kk < 4; ++kk) {
            const int kkg = ch * 4 + kk;
            const bf16x8 eA0 = *(const bf16x8*)&sE[kk][0][lane][0];
            const bf16x8 eA1 = *(const bf16x8*)&sE[kk][1][lane][0];
            const bf16x8 vB0 = *(const bf16x8*)&wvB0[(size_t)kkg * 512];
            const bf16x8 vB1 = *(const bf16x8*)&wvB1[(size_t)kkg * 512];
            const bf16x8 aS  = *(const bf16x8*)&aQK[(size_t)kkg * 512];
            const bf16x8 bS  = *(const bf16x8*)&bSrc[(size_t)kk * 512];
            accS = __builtin_amdgcn_mfma_f32_32x32x16_bf16(aS, bS, accS, 0, 0, 0);
            accV[0][0] = __builtin_amdgcn_mfma_f32_32x32x16_bf16(eA0, vB0, accV[0][0], 0, 0, 0);
            accV[0][1] = __builtin_amdgcn_mfma_f32_32x32x16_bf16(eA0, vB1, accV[0][1], 0, 0, 0);
            accV[1][0] = __builtin_amdgcn_mfma_f32_32x32x16_bf16(eA1, vB0, accV[1][0], 0, 0, 0);
            accV[1][1] = __builtin_amdgcn_mfma_f32_32x32x16_bf16(eA1, vB1, accV[1][1], 0, 0, 0);
        }
        __syncthreads();
    }

    // ---- Q/K epilogue: lane = one token (col within nt), reg-quads = 4 consecutive i
    {
        const float* bias = (w < 2) ? bq : bk;
        ushort_t* dst = (w < 2) ? qT : kT;
        const int nt = w & 1;
        const size_t base = ((size_t)b * NN + n0 + nt * 32 + col) * NI;
#pragma unroll
        for (int q = 0; q < 4; ++q) {
            const int i0 = 8 * q + 4 * h;
            const float x0 = accS[4 * q + 0] + bias[i0 + 0];
            const float x1 = accS[4 * q + 1] + bias[i0 + 1];
            const float x2 = accS[4 * q + 2] + bias[i0 + 2];
            const float x3 = accS[4 * q + 3] + bias[i0 + 3];
            uint2 pr; pr.x = pack2bf(x0, x1); pr.y = pack2bf(x2, x3);
            *(uint2*)&dst[base + i0] = pr;
        }
    }

    // ---- V epilogue: lane = one channel o, reg-quads = 4 consecutive tokens
#pragma unroll
    for (int cti = 0; cti < 2; ++cti) {
        const int o = (2 * w + cti) * 32 + col;
        const float vb = bv[o];
#pragma unroll
        for (int mt = 0; mt < 2; ++mt) {
#pragma unroll
            for (int q = 0; q < 4; ++q) {
                const int nst = n0 + mt * 32 + 8 * q + 4 * h;
                uint2 pr;
                pr.x = pack2bf(accV[mt][cti][4 * q + 0] + vb,
                               accV[mt][cti][4 * q + 1] + vb);
                pr.y = pack2bf(accV[mt][cti][4 * q + 2] + vb,
                               accV[mt][cti][4 * q + 3] + vb);
                *(uint2*)&vF[vfidx(b, nst, o)] = pr;
            }
        }
    }
}

// ---------------------------------------------------------------- barrier-free MFMA attention
// 512 thr / 8 waves, grid (NN/64, B) = 256 blocks. Wave w: kg = w>>1 (1024
// keys), qs = w&1 (q-strip) -> S computed exactly ONCE chip-wide (no dup).
// Each wave does PV for ALL 256 channels (acc[8] = 128 regs). V loads are
// fully coalesced via the vF frag-order layout. Fixed-base softmax. Zero
// k-loop barriers. launch_bounds(512,2) = 256 unified regs (R5 lesson: less
// spills catastrophically).
__global__ __launch_bounds__(512, 2) void attn_kernel(
    const ushort_t* __restrict__ qT, const ushort_t* __restrict__ kT,
    const ushort_t* __restrict__ vF, const float* __restrict__ feat,
    float* __restrict__ out)
{
    __shared__ float red[4][64][33];     // [kg][q][c], 33.8 KB
    __shared__ float lpart[4][2][32];
    __shared__ float linvS[64];

    const int tid  = threadIdx.x;
    const int b    = blockIdx.y;
    const int nq0  = blockIdx.x * 64;
    const int w    = tid >> 6;
    const int lane = tid & 63;
    const int col  = lane & 31;
    const int h    = lane >> 5;
    const int qs   = w & 1;        // q-strip
    const int kg   = w >> 1;       // key group

    // Q B-frags for this wave's q-strip only (constant across the k-loop)
    bf16x8 bQ0, bQ1;
    {
        const size_t qb = ((size_t)b * NN + nq0 + qs * 32 + col) * NI + h * 8;
        bQ0 = *(const bf16x8*)&qT[qb];
        bQ1 = *(const bf16x8*)&qT[qb + 16];
    }

    f32x16 acc[8];   // one 32x32 tile per c-strip (128 regs)
#pragma unroll
    for (int cs = 0; cs < 8; ++cs)
#pragma unroll
        for (int r = 0; r < 16; ++r) acc[cs][r] = 0.f;

    float lp = 0.f;   // row-sum partial (lane col = query)

    const size_t kTb = (size_t)b * NN * NI;
    const int keybase = kg * 1024;

    for (int strip = 0; strip < 32; ++strip) {
        const int key0 = keybase + strip * 32;

        // K A-frags: lane m = key, k = channel
        const size_t kb = kTb + (size_t)(key0 + col) * NI + h * 8;
        const bf16x8 aK0 = *(const bf16x8*)&kT[kb];
        const bf16x8 aK1 = *(const bf16x8*)&kT[kb + 16];

        // S^T subtile for this q-strip: lane col = query, regs = keys
        f32x16 st;
#pragma unroll
        for (int r = 0; r < 16; ++r) st[r] = 0.f;
        st = __builtin_amdgcn_mfma_f32_32x32x16_bf16(aK0, bQ0, st, 0, 0, 0);
        st = __builtin_amdgcn_mfma_f32_32x32x16_bf16(aK1, bQ1, st, 0, 0, 0);

        // p = exp(s); row-sum in fp32; truncation-pack to bf16 pairs
        float p[16]; float sum = 0.f;
#pragma unroll
        for (int r = 0; r < 16; ++r) { p[r] = __expf(st[r]); sum += p[r]; }
        lp += sum;

        uint32 pk[8];
#pragma unroll
        for (int j = 0; j < 8; ++j) pk[j] = pack2bf_t(p[2 * j], p[2 * j + 1]);
        uint32 rv[8];
#pragma unroll
        for (int j = 0; j < 8; ++j) rv[j] = __shfl_xor(pk[j], 32, 64);
        fragU F0, F1;    // A-frags: key chunks 0-15 / 16-31
        F0.u[0] = h ? rv[2] : pk[0];
        F0.u[1] = h ? rv[3] : pk[1];
        F0.u[2] = h ? pk[2] : rv[0];
        F0.u[3] = h ? pk[3] : rv[1];
        F1.u[0] = h ? rv[6] : pk[4];
        F1.u[1] = h ? rv[7] : pk[5];
        F1.u[2] = h ? pk[6] : rv[4];
        F1.u[3] = h ? pk[7] : rv[5];

        // PV over all 8 c-strips; V loads coalesced (lane-stride 16B)
        const size_t vbB = (((size_t)b * (NN / 16) + (key0 >> 4)) * 2 + h) * (CC * 8)
                         + (size_t)col * 8;
#pragma unroll
        for (int cs = 0; cs < 8; ++cs) {
            const bf16x8 v0 = *(const bf16x8*)&vF[vbB + cs * 256];
            const bf16x8 v1 = *(const bf16x8*)&vF[vbB + 4096 + cs * 256];
            acc[cs] = __builtin_amdgcn_mfma_f32_32x32x16_bf16(F0.v, v0, acc[cs], 0, 0, 0);
            acc[cs] = __builtin_amdgcn_mfma_f32_32x32x16_bf16(F1.v, v1, acc[cs], 0, 0, 0);
        }
    }

    // ---- combine row sums: halves, then the 4 key groups
    lp += __shfl_xor(lp, 32, 64);
    if (h == 0) lpart[kg][qs][col] = lp;
    __syncthreads();
    if (tid < 64) {
        const int s = tid >> 5, q = tid & 31;
        linvS[tid] = 1.0f / (lpart[0][s][q] + lpart[1][s][q] + lpart[2][s][q] + lpart[3][s][q]);
    }
    __syncthreads();

    const int c32 = tid >> 4;          // 0..31
    const int q4  = (tid & 15) * 4;    // 0..60
    float lv[4];
#pragma unroll
    for (int j = 0; j < 4; ++j) lv[j] = linvS[q4 + j];

    // ---- epilogue: 8 passes (one per c-strip); reduce over kg via LDS
#pragma unroll
    for (int pp = 0; pp < 8; ++pp) {
#pragma unroll
        for (int r = 0; r < 16; ++r) {
            const int row = qs * 32 + (r & 3) + 8 * (r >> 2) + 4 * h;
            red[kg][row][col] = acc[pp][r];
        }
        __syncthreads();
        {
            const int cglob = pp * 32 + c32;
            const size_t gb = ((size_t)b * CC + cglob) * NN + nq0 + q4;
            float o[4];
#pragma unroll
            for (int j = 0; j < 4; ++j)
                o[j] = red[0][q4 + j][c32] + red[1][q4 + j][c32]
                     + red[2][q4 + j][c32] + red[3][q4 + j][c32];
            const float4 f4 = *(const float4*)&feat[gb];
            float4 o4;
            o4.x = o[0] * lv[0] + f4.x;
            o4.y = o[1] * lv[1] + f4.y;
            o4.z = o[2] * lv[2] + f4.z;
            o4.w = o[3] * lv[3] + f4.w;
            *(float4*)&out[gb] = o4;
        }
        __syncthreads();
    }
}

// ---------------------------------------------------------------- launch
extern "C" void kernel_launch(void* const* d_in, const int* in_sizes, int n_in,
                              void* d_out, int out_size, void* d_ws, size_t ws_size,
                              hipStream_t stream)
{
    (void)in_sizes; (void)n_in; (void)out_size; (void)ws_size;
    const float* feat = (const float*)d_in[0];
    const float* edge = (const float*)d_in[1];
    const float* wq   = (const float*)d_in[2];
    const float* bq   = (const float*)d_in[3];
    const float* wk   = (const float*)d_in[4];
    const float* bk   = (const float*)d_in[5];
    const float* wv   = (const float*)d_in[6];
    const float* bv   = (const float*)d_in[7];
    float* out = (float*)d_out;

    // Workspace layout IDENTICAL to the previously-passing kernel (10 MB):
    ushort_t* qT  = (ushort_t*)d_ws;                      // [B][N][NI] bf16, 1 MB
    ushort_t* kT  = qT + (size_t)BB * NN * NI;            // [B][N][NI] bf16, 1 MB
    ushort_t* vF  = kT + (size_t)BB * NN * NI;            // frag-order V, 8 MB

    // Weight-frag scratch lives in the OUTPUT buffer (16 MB; attn_kernel
    // runs last and overwrites every element, so this is hazard-free).
    ushort_t* wvF = (ushort_t*)d_out;                     // 128 KB
    ushort_t* wqF = wvF + (size_t)CC * CC;                // 16 KB
    ushort_t* wkF = wqF + (size_t)NI * CC;                // 16 KB

    wconv_kernel<<<dim3(68), 256, 0, stream>>>(wq, wk, wv, wqF, wkF, wvF);
    proj_kernel<<<dim3(NN / 64, BB), 256, 0, stream>>>(feat, edge, wqF, wkF, wvF,
                                                       bq, bk, bv, qT, kT, vF);
    attn_kernel<<<dim3(NN / 64, BB), 512, 0, stream>>>(qT, kT, vF, feat, out);
}